// Round 2
// baseline (762.122 us; speedup 1.0000x reference)
//
#include <hip/hip_runtime.h>
#include <hip/hip_bf16.h>
#include <stdint.h>

#define B_ 64
#define S_ 1024
#define F_ 1024
#define U_ 1024

typedef __attribute__((ext_vector_type(4))) float  f4;
typedef __attribute__((ext_vector_type(4))) float  f32x4;
typedef __attribute__((ext_vector_type(8))) short  short8;
typedef unsigned int u32;

static __device__ __forceinline__ short f2bf(float x){
    union { float f; uint32_t u; } v; v.f = x;
    uint32_t u = v.u;
    u += 0x7fffu + ((u >> 16) & 1u);   // round-to-nearest-even
    return (short)(u >> 16);
}

static __device__ __forceinline__ void glds16(const void* g, void* l){
    __builtin_amdgcn_global_load_lds(
        (const __attribute__((address_space(1))) u32*)g,
        (__attribute__((address_space(3))) u32*)l, 16, 0, 0);
}

static __device__ __forceinline__ float fast_tanh(float x){
    float e = __expf(2.f * x);
    return 1.f - 2.f / (e + 1.f);
}

// ---------------------------------------------------------------------------
// Pack W1 [F,U] fp32 -> bf16 tiles in the exact LDS image the GEMM wants:
// tile (kb, nb) = 8KB at offset (kb*8+nb)*8192; inside: [kgrp 0..3][n 0..127][8 k]
// ---------------------------------------------------------------------------
__global__ void pack_w1(const float* __restrict__ W1, short* __restrict__ Bws){
    int g = blockIdx.x * 256 + threadIdx.x;      // 131072 groups of 8 bf16
    int n    =  g        & 127;
    int kgrp = (g >> 7)  & 3;
    int nb   = (g >> 9)  & 7;
    int kb   =  g >> 12;
    int u  = nb*128 + n;
    int f0 = kb*32 + kgrp*8;
    short8 o;
#pragma unroll
    for (int j = 0; j < 8; ++j)
        o[j] = f2bf(W1[(size_t)(f0 + j)*U_ + u]);
    *(short8*)&Bws[(size_t)g * 8] = o;
}

// ---------------------------------------------------------------------------
// Pack features [65536,1024] fp32 -> bf16 tiles, same per-tile image as W1:
// tile (mb, kt) at short offset (mb*32+kt)*4096; inside [kgrp][row128][8k]
// block: 256 thr = 64 rows x 4 kquads; grid 32768 = mb(512) x kt(32) x half(2)
// ---------------------------------------------------------------------------
__global__ void pack_feat(const float* __restrict__ F, short* __restrict__ out){
    int bid = blockIdx.x;
    int t = threadIdx.x;
    int half = bid & 1, kt = (bid >> 1) & 31, mb = bid >> 6;
    int row = half*64 + (t >> 2);
    int kq  = t & 3;
    const float* src = F + (size_t)(mb*128 + row)*1024 + kt*32 + kq*8;
    f4 a = *(const f4*)src;
    f4 b = *(const f4*)(src + 4);
    short8 o;
    o[0]=f2bf(a[0]); o[1]=f2bf(a[1]); o[2]=f2bf(a[2]); o[3]=f2bf(a[3]);
    o[4]=f2bf(b[0]); o[5]=f2bf(b[1]); o[6]=f2bf(b[2]); o[7]=f2bf(b[3]);
    *(short8*)&out[(size_t)(mb*32 + kt)*4096 + (kq*128 + row)*8] = o;
}

// ---------------------------------------------------------------------------
// hb[b][u] = hidden[b] @ W2[:,u] + W2_b[u] + W1_b[u]; 4 batches/block (W2 reuse)
// ---------------------------------------------------------------------------
__global__ void hb_kernel(const float* __restrict__ hidden, const float* __restrict__ W2,
                          const float* __restrict__ W2b, const float* __restrict__ W1b,
                          float* __restrict__ hb){
    __shared__ float hs[4][1024];
    int ub = blockIdx.x, bg = blockIdx.y, t = threadIdx.x;
    for (int i = t; i < 4096; i += 256) ((float*)hs)[i] = hidden[(size_t)bg*4096 + i];
    __syncthreads();
    int u = ub*256 + t;
    float base = W1b[u] + W2b[u];
    float a0 = 0.f, a1 = 0.f, a2 = 0.f, a3 = 0.f;
#pragma unroll 4
    for (int k = 0; k < 1024; ++k){
        float w = W2[(size_t)k*1024 + u];
        a0 = fmaf(hs[0][k], w, a0);
        a1 = fmaf(hs[1][k], w, a1);
        a2 = fmaf(hs[2][k], w, a2);
        a3 = fmaf(hs[3][k], w, a3);
    }
    hb[(size_t)(bg*4 + 0)*1024 + u] = base + a0;
    hb[(size_t)(bg*4 + 1)*1024 + u] = base + a1;
    hb[(size_t)(bg*4 + 2)*1024 + u] = base + a2;
    hb[(size_t)(bg*4 + 3)*1024 + u] = base + a3;
}

// ---------------------------------------------------------------------------
// XCD-grouped block swizzle: hw xcd = bid&7; all 8 nb-blocks of one mb land on
// the same XCD consecutively -> A panel + W1 stay in that XCD's L2.
// ---------------------------------------------------------------------------
static __device__ __forceinline__ void swz_mbnb(int bid, int& mb, int& nb){
    int xcd = bid & 7;
    int seq = bid >> 3;          // 0..511 within XCD
    nb = seq & 7;
    mb = xcd*64 + (seq >> 3);
}

// ---------------------------------------------------------------------------
// GEMM v2 (pure m97 structure): both operands pre-packed bf16, staged with
// global_load_lds(16B), double-buffered, 1 barrier/kt. Epilogue: tanh + V-dot.
// ---------------------------------------------------------------------------
__global__ __launch_bounds__(256) void gemm_v2(
        const short* __restrict__ Abf, const short* __restrict__ Bws,
        const float* __restrict__ hb, const float* __restrict__ Vw,
        float* __restrict__ logits){
    __shared__ short Ab[2][4096];      // 2 x 8 KB
    __shared__ short Bb[2][4096];

    const int t = threadIdx.x;
    int mb, nb; swz_mbnb(blockIdx.x, mb, nb);
    const int m0 = mb*128, n0 = nb*128;
    const int batch = m0 >> 10;
    const int w = t >> 6, l = t & 63;
    const int wr = w >> 1, wc = w & 1;
    const int kg = l >> 4, fr = l & 15;

    const char* Asrc = (const char*)Abf + ((size_t)(mb*32) << 13) + (w<<11) + (l<<4);
    const char* Bsrc = (const char*)Bws + ((size_t)nb << 13) + (w<<11) + (l<<4);
    char* AdstBase[2] = { (char*)&Ab[0][0] + (w<<11), (char*)&Ab[1][0] + (w<<11) };
    char* BdstBase[2] = { (char*)&Bb[0][0] + (w<<11), (char*)&Bb[1][0] + (w<<11) };

#define STAGE(sel, kt) do{                                   \
        const char* as_ = Asrc + ((size_t)(kt) << 13);       \
        const char* bs_ = Bsrc + ((size_t)(kt) << 16);       \
        glds16(as_,        AdstBase[sel]);                   \
        glds16(as_ + 1024, AdstBase[sel] + 1024);            \
        glds16(bs_,        BdstBase[sel]);                   \
        glds16(bs_ + 1024, BdstBase[sel] + 1024);            \
    }while(0)

    f32x4 acc[4][4];
#pragma unroll
    for (int i = 0; i < 4; ++i)
#pragma unroll
        for (int j = 0; j < 4; ++j) acc[i][j] = (f32x4)0.f;

    STAGE(0, 0);
    asm volatile("s_waitcnt vmcnt(0)");
    __syncthreads();

    for (int kt = 0; kt < 32; ++kt){
        const int sel = kt & 1;
        if (kt < 31) STAGE(sel ^ 1, kt + 1);

        short8 af[4], bfr[4];
#pragma unroll
        for (int i = 0; i < 4; ++i)
            af[i] = *(const short8*)&Ab[sel][(kg*128 + wr*64 + i*16 + fr)*8];
#pragma unroll
        for (int j = 0; j < 4; ++j)
            bfr[j] = *(const short8*)&Bb[sel][(kg*128 + wc*64 + j*16 + fr)*8];
#pragma unroll
        for (int i = 0; i < 4; ++i)
#pragma unroll
            for (int j = 0; j < 4; ++j)
                acc[i][j] = __builtin_amdgcn_mfma_f32_16x16x32_bf16(af[i], bfr[j], acc[i][j], 0, 0, 0);
        __syncthreads();               // drains vmcnt (prefetch) + lgkmcnt
    }
#undef STAGE

    float hv[4], vv[4];
#pragma unroll
    for (int j = 0; j < 4; ++j){
        int u = n0 + wc*64 + j*16 + fr;
        hv[j] = hb[batch*U_ + u];
        vv[j] = Vw[u];
    }
#pragma unroll
    for (int i = 0; i < 4; ++i){
#pragma unroll
        for (int reg = 0; reg < 4; ++reg){
            float sum = 0.f;
#pragma unroll
            for (int j = 0; j < 4; ++j){
                float sc = fast_tanh(acc[i][j][reg] + hv[j]);
                sum = fmaf(vv[j], sc, sum);
            }
            sum += __shfl_xor(sum, 1, 64);
            sum += __shfl_xor(sum, 2, 64);
            sum += __shfl_xor(sum, 4, 64);
            sum += __shfl_xor(sum, 8, 64);
            if (fr == 0)
                atomicAdd(&logits[m0 + wr*64 + i*16 + kg*4 + reg], sum);
        }
    }
}

// ---------------------------------------------------------------------------
// Fallback GEMM (round-1 structure, fp32 A inline cvt) + XCD swizzle — used
// only if ws_size can't hold the 128 MB packed-feature image.
// ---------------------------------------------------------------------------
__global__ __launch_bounds__(256) void gemm_fb(
        const float* __restrict__ A, const short* __restrict__ Bws,
        const float* __restrict__ hb, const float* __restrict__ Vw,
        float* __restrict__ logits){
    __shared__ short Abuf[4096];
    __shared__ short Bbuf[2][4096];

    const int t = threadIdx.x;
    int mb, nb; swz_mbnb(blockIdx.x, mb, nb);
    const int m0 = mb*128, n0 = nb*128;
    const int batch = m0 >> 10;
    const int w = t >> 6, l = t & 63;
    const int wr = w >> 1, wc = w & 1;
    const int kg = l >> 4, fr = l & 15;
    const int ar = t >> 1, ah = t & 1;

    const float* aptr = A + (size_t)(m0 + ar)*F_ + ah*16;

    f32x4 acc[4][4];
#pragma unroll
    for (int i = 0; i < 4; ++i)
#pragma unroll
        for (int j = 0; j < 4; ++j) acc[i][j] = (f32x4)0.f;

    f4 a0 = *(const f4*)(aptr + 0);
    f4 a1 = *(const f4*)(aptr + 4);
    f4 a2 = *(const f4*)(aptr + 8);
    f4 a3 = *(const f4*)(aptr + 12);
    {
        const char* src = (const char*)Bws + ((size_t)nb << 13) + (w<<11) + (l<<4);
        char* dst = (char*)&Bbuf[0][0] + (w<<11);
        glds16(src, dst);
        glds16(src + 1024, dst + 1024);
    }

    for (int kt = 0; kt < 32; ++kt){
        const int sel = kt & 1;
        short8 s0, s1;
        s0[0]=f2bf(a0[0]); s0[1]=f2bf(a0[1]); s0[2]=f2bf(a0[2]); s0[3]=f2bf(a0[3]);
        s0[4]=f2bf(a1[0]); s0[5]=f2bf(a1[1]); s0[6]=f2bf(a1[2]); s0[7]=f2bf(a1[3]);
        s1[0]=f2bf(a2[0]); s1[1]=f2bf(a2[1]); s1[2]=f2bf(a2[2]); s1[3]=f2bf(a2[3]);
        s1[4]=f2bf(a3[0]); s1[5]=f2bf(a3[1]); s1[6]=f2bf(a3[2]); s1[7]=f2bf(a3[3]);
        *(short8*)&Abuf[((2*ah+0)*128 + ar)*8] = s0;
        *(short8*)&Abuf[((2*ah+1)*128 + ar)*8] = s1;
        __syncthreads();

        if (kt < 31){
            const float* ap = aptr + (kt+1)*32;
            a0 = *(const f4*)(ap + 0);
            a1 = *(const f4*)(ap + 4);
            a2 = *(const f4*)(ap + 8);
            a3 = *(const f4*)(ap + 12);
            const char* src = (const char*)Bws + ((size_t)((kt+1)*8 + nb) << 13) + (w<<11) + (l<<4);
            char* dst = (char*)&Bbuf[sel^1][0] + (w<<11);
            glds16(src, dst);
            glds16(src + 1024, dst + 1024);
        }

        short8 af[4], bfr[4];
#pragma unroll
        for (int i = 0; i < 4; ++i)
            af[i] = *(const short8*)&Abuf[(kg*128 + wr*64 + i*16 + fr)*8];
#pragma unroll
        for (int j = 0; j < 4; ++j)
            bfr[j] = *(const short8*)&Bbuf[sel][(kg*128 + wc*64 + j*16 + fr)*8];
#pragma unroll
        for (int i = 0; i < 4; ++i)
#pragma unroll
            for (int j = 0; j < 4; ++j)
                acc[i][j] = __builtin_amdgcn_mfma_f32_16x16x32_bf16(af[i], bfr[j], acc[i][j], 0, 0, 0);
        __syncthreads();
    }

    float hv[4], vv[4];
#pragma unroll
    for (int j = 0; j < 4; ++j){
        int u = n0 + wc*64 + j*16 + fr;
        hv[j] = hb[batch*U_ + u];
        vv[j] = Vw[u];
    }
#pragma unroll
    for (int i = 0; i < 4; ++i){
#pragma unroll
        for (int reg = 0; reg < 4; ++reg){
            float sum = 0.f;
#pragma unroll
            for (int j = 0; j < 4; ++j){
                float sc = fast_tanh(acc[i][j][reg] + hv[j]);
                sum = fmaf(vv[j], sc, sum);
            }
            sum += __shfl_xor(sum, 1, 64);
            sum += __shfl_xor(sum, 2, 64);
            sum += __shfl_xor(sum, 4, 64);
            sum += __shfl_xor(sum, 8, 64);
            if (fr == 0)
                atomicAdd(&logits[m0 + wr*64 + i*16 + kg*4 + reg], sum);
        }
    }
}

// ---------------------------------------------------------------------------
// softmax over S per batch, in place
// ---------------------------------------------------------------------------
__global__ void softmax_seq(float* __restrict__ lg){
    __shared__ float red[4], red2[4];
    int b = blockIdx.x, t = threadIdx.x;
    float v[4];
#pragma unroll
    for (int c = 0; c < 4; ++c) v[c] = lg[b*1024 + c*256 + t];
    float mx = fmaxf(fmaxf(v[0], v[1]), fmaxf(v[2], v[3]));
#pragma unroll
    for (int off = 32; off >= 1; off >>= 1) mx = fmaxf(mx, __shfl_xor(mx, off, 64));
    if ((t & 63) == 0) red[t >> 6] = mx;
    __syncthreads();
    mx = fmaxf(fmaxf(red[0], red[1]), fmaxf(red[2], red[3]));
    float e[4], s = 0.f;
#pragma unroll
    for (int c = 0; c < 4; ++c){ e[c] = __expf(v[c] - mx); s += e[c]; }
#pragma unroll
    for (int off = 32; off >= 1; off >>= 1) s += __shfl_xor(s, off, 64);
    if ((t & 63) == 0) red2[t >> 6] = s;
    __syncthreads();
    s = red2[0] + red2[1] + red2[2] + red2[3];
    float inv = 1.f / s;
#pragma unroll
    for (int c = 0; c < 4; ++c) lg[b*1024 + c*256 + t] = e[c] * inv;
}

// ---------------------------------------------------------------------------
// context[b][f] = sum_s w[b,s]*features[b,s,f]; float4 loads, 1 KB/wave-inst
// grid (8 s-chunks, 64 b); 4 atomics per thread at the end
// ---------------------------------------------------------------------------
__global__ void context_kernel(const float* __restrict__ feats, const float* __restrict__ wts,
                               float* __restrict__ ctx){
    __shared__ float wsh[128];
    int sh = blockIdx.x, b = blockIdx.y, t = threadIdx.x;
    if (t < 128) wsh[t] = wts[b*1024 + sh*128 + t];
    __syncthreads();
    const f4* fp = (const f4*)(feats + ((size_t)b*1024 + sh*128)*1024) + t;
    f4 a0 = (f4)0.f, a1 = (f4)0.f, a2 = (f4)0.f, a3 = (f4)0.f;
    for (int s = 0; s < 128; s += 4){
        a0 += wsh[s+0] * fp[(size_t)(s+0)*256];
        a1 += wsh[s+1] * fp[(size_t)(s+1)*256];
        a2 += wsh[s+2] * fp[(size_t)(s+2)*256];
        a3 += wsh[s+3] * fp[(size_t)(s+3)*256];
    }
    f4 r = (a0 + a1) + (a2 + a3);
    float* c = ctx + b*1024 + t*4;
    atomicAdd(c+0, r[0]); atomicAdd(c+1, r[1]);
    atomicAdd(c+2, r[2]); atomicAdd(c+3, r[3]);
}

// ---------------------------------------------------------------------------
extern "C" void kernel_launch(void* const* d_in, const int* in_sizes, int n_in,
                              void* d_out, int out_size, void* d_ws, size_t ws_size,
                              hipStream_t stream){
    const float* features = (const float*)d_in[0];
    const float* hidden   = (const float*)d_in[1];
    const float* W1w      = (const float*)d_in[2];
    const float* W1b      = (const float*)d_in[3];
    const float* W2w      = (const float*)d_in[4];
    const float* W2b      = (const float*)d_in[5];
    const float* Vw       = (const float*)d_in[6];
    // d_in[7] = V_b: uniform over seq -> softmax-invariant; skipped.

    float* out = (float*)d_out;
    float* ctx = out;            // [64*1024]
    float* att = out + 65536;    // [64*1024] logits -> weights in place

    short* Bws    = (short*)d_ws;                                    // 2 MB packed W1
    float* hb     = (float*)((char*)d_ws + (size_t)2*1024*1024);     // 256 KB
    short* featbf = (short*)((char*)d_ws + (size_t)2*1024*1024 + 256*1024); // 128 MB

    const size_t need = (size_t)2*1024*1024 + 256*1024 + (size_t)128*1024*1024;

    hipMemsetAsync(d_out, 0, (size_t)131072 * sizeof(float), stream);
    pack_w1<<<512, 256, 0, stream>>>(W1w, Bws);
    hb_kernel<<<dim3(4, 16), 256, 0, stream>>>(hidden, W2w, W2b, W1b, hb);

    if (ws_size >= need){
        pack_feat<<<32768, 256, 0, stream>>>(features, featbf);
        gemm_v2<<<4096, 256, 0, stream>>>(featbf, Bws, hb, Vw, att);
    } else {
        gemm_fb<<<4096, 256, 0, stream>>>(features, Bws, hb, Vw, att);
    }

    softmax_seq<<<64, 256, 0, stream>>>(att);
    context_kernel<<<dim3(8, 64), 256, 0, stream>>>(features, att, ctx);
}

// Round 5
// 674.703 us; speedup vs baseline: 1.1296x; 1.1296x over previous
//
#include <hip/hip_runtime.h>
#include <hip/hip_bf16.h>
#include <stdint.h>

#define B_ 64
#define S_ 1024
#define F_ 1024
#define U_ 1024

typedef __attribute__((ext_vector_type(4))) float  f4;
typedef __attribute__((ext_vector_type(4))) float  f32x4;
typedef __attribute__((ext_vector_type(8))) short  short8;
typedef __attribute__((ext_vector_type(4))) short  bf16x4;
typedef unsigned int u32;

static __device__ __forceinline__ short f2bf(float x){
    union { float f; uint32_t u; } v; v.f = x;
    uint32_t u = v.u;
    u += 0x7fffu + ((u >> 16) & 1u);   // round-to-nearest-even
    return (short)(u >> 16);
}

static __device__ __forceinline__ void glds16(const void* g, void* l){
    __builtin_amdgcn_global_load_lds(
        (const __attribute__((address_space(1))) u32*)g,
        (__attribute__((address_space(3))) u32*)l, 16, 0, 0);
}

static __device__ __forceinline__ float fast_tanh(float x){
    float e = __expf(2.f * x);
    return 1.f - 2.f / (e + 1.f);
}

// ---------------------------------------------------------------------------
// Pack W1 [F,U] fp32 -> bf16 tiles in the exact LDS image the GEMM wants:
// tile (kb, nb) = 8KB at offset (kb*8+nb)*8192B; inside: [kgrp 0..3][n 0..127][8 k]
// ---------------------------------------------------------------------------
__global__ void pack_w1(const float* __restrict__ W1, short* __restrict__ Bws){
    int g = blockIdx.x * 256 + threadIdx.x;      // 131072 groups of 8 bf16
    int n    =  g        & 127;
    int kgrp = (g >> 7)  & 3;
    int nb   = (g >> 9)  & 7;
    int kb   =  g >> 12;
    int u  = nb*128 + n;
    int f0 = kb*32 + kgrp*8;
    short8 o;
#pragma unroll
    for (int j = 0; j < 8; ++j)
        o[j] = f2bf(W1[(size_t)(f0 + j)*U_ + u]);
    *(short8*)&Bws[(size_t)g * 8] = o;
}

// ---------------------------------------------------------------------------
// Pack features fp32 -> bf16 tiles via LDS transpose.
// Block = one (mb, kt) tile: reads [128 rows][32 k] fp32 with 128B-coalesced
// loads, writes the 8 KB packed image [kgrp][row][8k] with CONTIGUOUS stores.
// Tile image = 4096 shorts = 512 short8 entries (store loop is i<2!).
// grid = 512 mb x 32 kt = 16384 blocks.
// ---------------------------------------------------------------------------
__global__ __launch_bounds__(256) void pack_feat(const float* __restrict__ F,
                                                 short* __restrict__ out){
    __shared__ short tile[4096];                  // 8 KB packed image
    const int mb = blockIdx.x >> 5, kt = blockIdx.x & 31;
    const int t = threadIdx.x;
    const float* base = F + (size_t)mb*128*1024 + kt*32;
#pragma unroll
    for (int i = 0; i < 4; ++i){
        int li = i*256 + t;                       // f4 index in [128 rows][8 c4]
        int row = li >> 3, c4 = li & 7;
        f4 v = *(const f4*)(base + (size_t)row*1024 + c4*4);
        bf16x4 s;
        s[0]=f2bf(v[0]); s[1]=f2bf(v[1]); s[2]=f2bf(v[2]); s[3]=f2bf(v[3]);
        int kgrp = c4 >> 1, half = c4 & 1;
        *(bf16x4*)&tile[(kgrp*128 + row)*8 + half*4] = s;
    }
    __syncthreads();
    short8* dst = (short8*)&out[(size_t)blockIdx.x * 4096];
#pragma unroll
    for (int i = 0; i < 2; ++i){                  // 512 short8 = 4096 shorts
        int e = i*256 + t;
        dst[e] = *(const short8*)&tile[e*8];      // contiguous 16B/lane stores
    }
}

// ---------------------------------------------------------------------------
// hb[b][u] = hidden[b] @ W2[:,u] + W2_b[u] + W1_b[u]
// K-split x4 for occupancy: grid (ub 4, kc 4, bg 16) = 256 blocks, atomicAdd.
// hb must be zeroed before launch.
// ---------------------------------------------------------------------------
__global__ void hb_kernel(const float* __restrict__ hidden, const float* __restrict__ W2,
                          const float* __restrict__ W2b, const float* __restrict__ W1b,
                          float* __restrict__ hb){
    __shared__ float hs[4][256];
    const int ub = blockIdx.x, kc = blockIdx.y, bg = blockIdx.z, t = threadIdx.x;
    for (int i = t; i < 1024; i += 256)
        hs[i>>8][i&255] = hidden[(size_t)(bg*4 + (i>>8))*1024 + kc*256 + (i&255)];
    __syncthreads();
    const int u = ub*256 + t;
    const float* w2 = W2 + (size_t)(kc*256)*1024 + u;
    float a0=0.f, a1=0.f, a2=0.f, a3=0.f;
#pragma unroll 4
    for (int k = 0; k < 256; ++k){
        float w = w2[(size_t)k*1024];
        a0 = fmaf(hs[0][k], w, a0);
        a1 = fmaf(hs[1][k], w, a1);
        a2 = fmaf(hs[2][k], w, a2);
        a3 = fmaf(hs[3][k], w, a3);
    }
    float base = (kc == 0) ? (W1b[u] + W2b[u]) : 0.f;
    atomicAdd(&hb[(size_t)(bg*4+0)*1024 + u], base + a0);
    atomicAdd(&hb[(size_t)(bg*4+1)*1024 + u], base + a1);
    atomicAdd(&hb[(size_t)(bg*4+2)*1024 + u], base + a2);
    atomicAdd(&hb[(size_t)(bg*4+3)*1024 + u], base + a3);
}

// ---------------------------------------------------------------------------
// XCD-grouped block swizzle: hw xcd = bid&7; all 8 nb-blocks of one mb land on
// the same XCD consecutively -> A panel + W1 stay in that XCD's L2.
// (4096 % 8 == 0 -> bijective.)
// ---------------------------------------------------------------------------
static __device__ __forceinline__ void swz_mbnb(int bid, int& mb, int& nb){
    int xcd = bid & 7;
    int seq = bid >> 3;          // 0..511 within XCD
    nb = seq & 7;
    mb = xcd*64 + (seq >> 3);
}

// ---------------------------------------------------------------------------
// GEMM (m97 structure): both operands pre-packed bf16, staged with
// global_load_lds(16B), double-buffered, manual unroll-2 so all LDS buffer
// selects are compile-time (no runtime-indexed arrays). Epilogue: tanh+V-dot.
// ---------------------------------------------------------------------------
__global__ __launch_bounds__(256) void gemm_v2(
        const short* __restrict__ Abf, const short* __restrict__ Bws,
        const float* __restrict__ hb, const float* __restrict__ Vw,
        float* __restrict__ logits){
    __shared__ short Ab0[4096], Ab1[4096];        // 4 x 8 KB
    __shared__ short Bb0[4096], Bb1[4096];

    const int t = threadIdx.x;
    int mb, nb; swz_mbnb(blockIdx.x, mb, nb);
    const int m0 = mb*128, n0 = nb*128;
    const int batch = m0 >> 10;
    const int w = t >> 6, l = t & 63;
    const int wr = w >> 1, wc = w & 1;
    const int kg = l >> 4, fr = l & 15;

    const char* Asrc = (const char*)Abf + ((size_t)(mb*32) << 13) + (w<<11) + (l<<4);
    const char* Bsrc = (const char*)Bws + ((size_t)nb << 13) + (w<<11) + (l<<4);
    char* Adst0 = (char*)Ab0 + (w<<11);  char* Adst1 = (char*)Ab1 + (w<<11);
    char* Bdst0 = (char*)Bb0 + (w<<11);  char* Bdst1 = (char*)Bb1 + (w<<11);

#define STAGE(D, kt) do{                                     \
        const char* as_ = Asrc + ((size_t)(kt) << 13);       \
        const char* bs_ = Bsrc + ((size_t)(kt) << 16);       \
        glds16(as_,        Adst##D);                         \
        glds16(as_ + 1024, Adst##D + 1024);                  \
        glds16(bs_,        Bdst##D);                         \
        glds16(bs_ + 1024, Bdst##D + 1024);                  \
    }while(0)

#define COMPUTE(AB, BB) do{                                                   \
        short8 af[4], bfr[4];                                                 \
        _Pragma("unroll")                                                     \
        for (int i = 0; i < 4; ++i)                                           \
            af[i] = *(const short8*)&AB[(kg*128 + wr*64 + i*16 + fr)*8];      \
        _Pragma("unroll")                                                     \
        for (int j = 0; j < 4; ++j)                                           \
            bfr[j] = *(const short8*)&BB[(kg*128 + wc*64 + j*16 + fr)*8];     \
        _Pragma("unroll")                                                     \
        for (int i = 0; i < 4; ++i)                                           \
            _Pragma("unroll")                                                 \
            for (int j = 0; j < 4; ++j)                                       \
                acc[i][j] = __builtin_amdgcn_mfma_f32_16x16x32_bf16(          \
                                af[i], bfr[j], acc[i][j], 0, 0, 0);           \
    }while(0)

    f32x4 acc[4][4];
#pragma unroll
    for (int i = 0; i < 4; ++i)
#pragma unroll
        for (int j = 0; j < 4; ++j) acc[i][j] = (f32x4)0.f;

    STAGE(0, 0);
    asm volatile("s_waitcnt vmcnt(0)");
    __syncthreads();

    for (int kt = 0; kt < 32; kt += 2){
        STAGE(1, kt + 1);          // prefetch odd tile while computing even
        COMPUTE(Ab0, Bb0);
        __syncthreads();           // drains prefetch vmcnt + lgkmcnt
        if (kt + 2 < 32) STAGE(0, kt + 2);
        COMPUTE(Ab1, Bb1);
        __syncthreads();
    }
#undef STAGE
#undef COMPUTE

    float hv[4], vv[4];
#pragma unroll
    for (int j = 0; j < 4; ++j){
        int u = n0 + wc*64 + j*16 + fr;
        hv[j] = hb[batch*U_ + u];
        vv[j] = Vw[u];
    }
#pragma unroll
    for (int i = 0; i < 4; ++i){
#pragma unroll
        for (int reg = 0; reg < 4; ++reg){
            float sum = 0.f;
#pragma unroll
            for (int j = 0; j < 4; ++j){
                float sc = fast_tanh(acc[i][j][reg] + hv[j]);
                sum = fmaf(vv[j], sc, sum);
            }
            sum += __shfl_xor(sum, 1, 64);
            sum += __shfl_xor(sum, 2, 64);
            sum += __shfl_xor(sum, 4, 64);
            sum += __shfl_xor(sum, 8, 64);
            if (fr == 0)
                atomicAdd(&logits[m0 + wr*64 + i*16 + kg*4 + reg], sum);
        }
    }
}

// ---------------------------------------------------------------------------
// Fallback GEMM (fp32 A inline cvt) — only if ws can't hold packed features.
// ---------------------------------------------------------------------------
__global__ __launch_bounds__(256) void gemm_fb(
        const float* __restrict__ A, const short* __restrict__ Bws,
        const float* __restrict__ hb, const float* __restrict__ Vw,
        float* __restrict__ logits){
    __shared__ short Abuf[4096];
    __shared__ short Bbuf[2][4096];

    const int t = threadIdx.x;
    int mb, nb; swz_mbnb(blockIdx.x, mb, nb);
    const int m0 = mb*128, n0 = nb*128;
    const int batch = m0 >> 10;
    const int w = t >> 6, l = t & 63;
    const int wr = w >> 1, wc = w & 1;
    const int kg = l >> 4, fr = l & 15;
    const int ar = t >> 1, ah = t & 1;

    const float* aptr = A + (size_t)(m0 + ar)*F_ + ah*16;

    f32x4 acc[4][4];
#pragma unroll
    for (int i = 0; i < 4; ++i)
#pragma unroll
        for (int j = 0; j < 4; ++j) acc[i][j] = (f32x4)0.f;

    f4 a0 = *(const f4*)(aptr + 0);
    f4 a1 = *(const f4*)(aptr + 4);
    f4 a2 = *(const f4*)(aptr + 8);
    f4 a3 = *(const f4*)(aptr + 12);
    {
        const char* src = (const char*)Bws + ((size_t)nb << 13) + (w<<11) + (l<<4);
        char* dst = (char*)&Bbuf[0][0] + (w<<11);
        glds16(src, dst);
        glds16(src + 1024, dst + 1024);
    }

    for (int kt = 0; kt < 32; ++kt){
        const int sel = kt & 1;
        short8 s0, s1;
        s0[0]=f2bf(a0[0]); s0[1]=f2bf(a0[1]); s0[2]=f2bf(a0[2]); s0[3]=f2bf(a0[3]);
        s0[4]=f2bf(a1[0]); s0[5]=f2bf(a1[1]); s0[6]=f2bf(a1[2]); s0[7]=f2bf(a1[3]);
        s1[0]=f2bf(a2[0]); s1[1]=f2bf(a2[1]); s1[2]=f2bf(a2[2]); s1[3]=f2bf(a2[3]);
        s1[4]=f2bf(a3[0]); s1[5]=f2bf(a3[1]); s1[6]=f2bf(a3[2]); s1[7]=f2bf(a3[3]);
        *(short8*)&Abuf[((2*ah+0)*128 + ar)*8] = s0;
        *(short8*)&Abuf[((2*ah+1)*128 + ar)*8] = s1;
        __syncthreads();

        if (kt < 31){
            const float* ap = aptr + (kt+1)*32;
            a0 = *(const f4*)(ap + 0);
            a1 = *(const f4*)(ap + 4);
            a2 = *(const f4*)(ap + 8);
            a3 = *(const f4*)(ap + 12);
            const char* src = (const char*)Bws + ((size_t)((kt+1)*8 + nb) << 13) + (w<<11) + (l<<4);
            char* dst = (char*)&Bbuf[sel^1][0] + (w<<11);
            glds16(src, dst);
            glds16(src + 1024, dst + 1024);
        }

        short8 af[4], bfr[4];
#pragma unroll
        for (int i = 0; i < 4; ++i)
            af[i] = *(const short8*)&Abuf[(kg*128 + wr*64 + i*16 + fr)*8];
#pragma unroll
        for (int j = 0; j < 4; ++j)
            bfr[j] = *(const short8*)&Bbuf[sel][(kg*128 + wc*64 + j*16 + fr)*8];
#pragma unroll
        for (int i = 0; i < 4; ++i)
#pragma unroll
            for (int j = 0; j < 4; ++j)
                acc[i][j] = __builtin_amdgcn_mfma_f32_16x16x32_bf16(af[i], bfr[j], acc[i][j], 0, 0, 0);
        __syncthreads();
    }

    float hv[4], vv[4];
#pragma unroll
    for (int j = 0; j < 4; ++j){
        int u = n0 + wc*64 + j*16 + fr;
        hv[j] = hb[batch*U_ + u];
        vv[j] = Vw[u];
    }
#pragma unroll
    for (int i = 0; i < 4; ++i){
#pragma unroll
        for (int reg = 0; reg < 4; ++reg){
            float sum = 0.f;
#pragma unroll
            for (int j = 0; j < 4; ++j){
                float sc = fast_tanh(acc[i][j][reg] + hv[j]);
                sum = fmaf(vv[j], sc, sum);
            }
            sum += __shfl_xor(sum, 1, 64);
            sum += __shfl_xor(sum, 2, 64);
            sum += __shfl_xor(sum, 4, 64);
            sum += __shfl_xor(sum, 8, 64);
            if (fr == 0)
                atomicAdd(&logits[m0 + wr*64 + i*16 + kg*4 + reg], sum);
        }
    }
}

// ---------------------------------------------------------------------------
// softmax over S per batch, in place
// ---------------------------------------------------------------------------
__global__ void softmax_seq(float* __restrict__ lg){
    __shared__ float red[4], red2[4];
    int b = blockIdx.x, t = threadIdx.x;
    float v[4];
#pragma unroll
    for (int c = 0; c < 4; ++c) v[c] = lg[b*1024 + c*256 + t];
    float mx = fmaxf(fmaxf(v[0], v[1]), fmaxf(v[2], v[3]));
#pragma unroll
    for (int off = 32; off >= 1; off >>= 1) mx = fmaxf(mx, __shfl_xor(mx, off, 64));
    if ((t & 63) == 0) red[t >> 6] = mx;
    __syncthreads();
    mx = fmaxf(fmaxf(red[0], red[1]), fmaxf(red[2], red[3]));
    float e[4], s = 0.f;
#pragma unroll
    for (int c = 0; c < 4; ++c){ e[c] = __expf(v[c] - mx); s += e[c]; }
#pragma unroll
    for (int off = 32; off >= 1; off >>= 1) s += __shfl_xor(s, off, 64);
    if ((t & 63) == 0) red2[t >> 6] = s;
    __syncthreads();
    s = red2[0] + red2[1] + red2[2] + red2[3];
    float inv = 1.f / s;
#pragma unroll
    for (int c = 0; c < 4; ++c) lg[b*1024 + c*256 + t] = e[c] * inv;
}

// ---------------------------------------------------------------------------
// context[b][f] = sum_s w[b,s]*features[b,s,f]; float4 loads
// ---------------------------------------------------------------------------
__global__ void context_kernel(const float* __restrict__ feats, const float* __restrict__ wts,
                               float* __restrict__ ctx){
    __shared__ float wsh[128];
    int sh = blockIdx.x, b = blockIdx.y, t = threadIdx.x;
    if (t < 128) wsh[t] = wts[b*1024 + sh*128 + t];
    __syncthreads();
    const f4* fp = (const f4*)(feats + ((size_t)b*1024 + sh*128)*1024) + t;
    f4 a0 = (f4)0.f, a1 = (f4)0.f, a2 = (f4)0.f, a3 = (f4)0.f;
    for (int s = 0; s < 128; s += 4){
        a0 += wsh[s+0] * fp[(size_t)(s+0)*256];
        a1 += wsh[s+1] * fp[(size_t)(s+1)*256];
        a2 += wsh[s+2] * fp[(size_t)(s+2)*256];
        a3 += wsh[s+3] * fp[(size_t)(s+3)*256];
    }
    f4 r = (a0 + a1) + (a2 + a3);
    float* c = ctx + b*1024 + t*4;
    atomicAdd(c+0, r[0]); atomicAdd(c+1, r[1]);
    atomicAdd(c+2, r[2]); atomicAdd(c+3, r[3]);
}

// ---------------------------------------------------------------------------
extern "C" void kernel_launch(void* const* d_in, const int* in_sizes, int n_in,
                              void* d_out, int out_size, void* d_ws, size_t ws_size,
                              hipStream_t stream){
    const float* features = (const float*)d_in[0];
    const float* hidden   = (const float*)d_in[1];
    const float* W1w      = (const float*)d_in[2];
    const float* W1b      = (const float*)d_in[3];
    const float* W2w      = (const float*)d_in[4];
    const float* W2b      = (const float*)d_in[5];
    const float* Vw       = (const float*)d_in[6];
    // d_in[7] = V_b: uniform over seq -> softmax-invariant; skipped.

    float* out = (float*)d_out;
    float* ctx = out;            // [64*1024]
    float* att = out + 65536;    // [64*1024] logits -> weights in place

    short* Bws    = (short*)d_ws;                                    // 2 MB packed W1
    float* hb     = (float*)((char*)d_ws + (size_t)2*1024*1024);     // 256 KB
    short* featbf = (short*)((char*)d_ws + (size_t)2*1024*1024 + 256*1024); // 128 MB

    const size_t need = (size_t)2*1024*1024 + 256*1024 + (size_t)128*1024*1024;

    (void)hipMemsetAsync(d_out, 0, (size_t)131072 * sizeof(float), stream);
    (void)hipMemsetAsync(hb, 0, (size_t)65536 * sizeof(float), stream);
    pack_w1<<<512, 256, 0, stream>>>(W1w, Bws);
    hb_kernel<<<dim3(4, 4, 16), 256, 0, stream>>>(hidden, W2w, W2b, W1b, hb);

    if (ws_size >= need){
        pack_feat<<<16384, 256, 0, stream>>>(features, featbf);
        gemm_v2<<<4096, 256, 0, stream>>>(featbf, Bws, hb, Vw, att);
    } else {
        gemm_fb<<<4096, 256, 0, stream>>>(features, Bws, hb, Vw, att);
    }

    softmax_seq<<<64, 256, 0, stream>>>(att);
    context_kernel<<<dim3(8, 64), 256, 0, stream>>>(features, att, ctx);
}